// Round 7
// baseline (188.763 us; speedup 1.0000x reference)
//
#include <hip/hip_runtime.h>

typedef unsigned short u16t;
typedef unsigned int   u32t;
typedef __bf16 bf16x8 __attribute__((ext_vector_type(8)));
typedef float  f32x4  __attribute__((ext_vector_type(4)));

#define NB   64
#define DIN  1024
#define DOUT 256
#define EPS  1e-4f   // LR*LR
#define KP   68      // LDS row stride in u16 (136B: 8B-aligned rows, 34 dw == 2 mod 32)

#define OUT_STATE (NB*DIN*DOUT)
#define OUT_LL    (OUT_STATE + 1)
#define OUT_RR    (OUT_LL + NB*DIN)

__device__ __forceinline__ u16t f2b(float x) {
    u32t u = __builtin_bit_cast(u32t, x);
    u += 0x7FFFu + ((u >> 16) & 1u);          // RTNE
    return (u16t)(u >> 16);
}
__device__ __forceinline__ float b2f(u16t h) {
    return __builtin_bit_cast(float, ((u32t)h) << 16);
}
__device__ __forceinline__ bf16x8 ld_frag(const u16t* p) {
    uint2 lo = *(const uint2*)(p);
    uint2 hi = *(const uint2*)(p + 4);
    union { uint4 u; bf16x8 v; } x;
    x.u = make_uint4(lo.x, lo.y, hi.x, hi.y);
    return x.v;
}
__device__ __forceinline__ void st8(u16t* p, u32t a, u32t b) {
    *(uint2*)(p) = make_uint2(a, b);
}

// ============================================================
// K1: grad row moments -> ll (out), GH = bf16(a*grad), col partials CP.
// No LDS. grid 2048 = (32 chunks x 64 n), block 256 (4 waves x 8 rows).
// bid = chunk*64 + n  ->  bid&7 == n&7 (XCD locality).
// ============================================================
__global__ __launch_bounds__(256) void k_prep(
    const float* __restrict__ grad, const float* __restrict__ L0,
    float* __restrict__ out, u16t* __restrict__ GH, float* __restrict__ CP)
{
    const int bid = blockIdx.x;
    const int n = bid & 63;
    const int chunk = bid >> 6;                 // 0..31
    const int wave = threadIdx.x >> 6, lane = threadIdx.x & 63;
    const float* gb = grad + ((size_t)n << 18);
    u16t* GHn = GH + ((size_t)n << 18);

    float4 cacc = {0.f, 0.f, 0.f, 0.f};
    const int i0 = chunk * 32 + wave * 8;
    #pragma unroll
    for (int r = 0; r < 8; ++r) {
        const int i = i0 + r;
        const float4 v = *(const float4*)(gb + (size_t)i * 256 + lane * 4);
        float s = v.x*v.x + v.y*v.y + v.z*v.z + v.w*v.w;
        cacc.x += v.x*v.x; cacc.y += v.y*v.y; cacc.z += v.z*v.z; cacc.w += v.w*v.w;
        #pragma unroll
        for (int off = 32; off; off >>= 1) s += __shfl_xor(s, off);
        const float l0 = L0[n * DIN + i];
        const float ll = fmaxf(l0, 0.5f * l0 + s * (0.5f / DOUT));
        const float a  = rsqrtf(sqrtf(ll));
        ushort4 g4v = { f2b(v.x*a), f2b(v.y*a), f2b(v.z*a), f2b(v.w*a) };
        *(ushort4*)(GHn + (size_t)i * 256 + lane * 4) = g4v;
        if (lane == 0) out[OUT_LL + n * DIN + i] = ll;
    }
    const int slot = chunk * 4 + wave;          // 0..127
    *(float4*)(CP + ((size_t)(n * 128 + slot)) * 256 + lane * 4) = cacc;
}

// ============================================================
// K2: reduce 128 col partials -> rr (out), BS = rr^-1/4 ; copy state
// ============================================================
__global__ __launch_bounds__(256) void k_cols(
    const float* __restrict__ R0, const float* __restrict__ state,
    float* __restrict__ out, float* __restrict__ BS, const float* __restrict__ CP)
{
    const int n = blockIdx.x, o = threadIdx.x;
    const float* cp = CP + (size_t)n * 128 * 256 + o;
    float s = 0.f;
    #pragma unroll 8
    for (int k = 0; k < 128; ++k) s += cp[k * 256];
    const float r0 = R0[n * DOUT + o];
    const float rr = fmaxf(r0, 0.5f * r0 + s * (0.5f / DIN));
    out[OUT_RR + n * DOUT + o] = rr;
    BS[n * DOUT + o] = rsqrtf(sqrtf(rr));
    if (n == 0 && o == 0) out[OUT_STATE] = state[0];
}

// ============================================================
// G1 (k_T): TT[o][p] = b[o] * sum_i GH[i][o] * M[i][p]
// 256 thr (4 waves 2x2, wave-tile 32x32), block tile 64o x 64p, K=1024.
// grid 1024 = (16 tiles x 64 n). 4 blocks/CU.
// ============================================================
__global__ __launch_bounds__(256, 4) void k_T(
    const u16t* __restrict__ GH, const float* __restrict__ M,
    const float* __restrict__ BS, u16t* __restrict__ TT)
{
    __shared__ u16t sA[64 * KP];   // [o][i]
    __shared__ u16t sB[64 * KP];   // [p][i]
    const int bid = blockIdx.x;
    const int n = bid & 63;
    const int tile = bid >> 6;                  // 0..15
    const int o0 = (tile & 3) * 64, p0 = (tile >> 2) * 64;
    const int t = threadIdx.x, lane = t & 63, w = t >> 6;
    const int wr = w >> 1, wc = w & 1, t16 = lane & 15, g4 = lane >> 4;
    const int cA = t & 63, ig = t >> 6;         // staging: row, i-group
    const u16t* GHn = GH + ((size_t)n << 18);
    const float* Mn = M + ((size_t)n << 18);
    u16t rA[16]; float rB[16];
    f32x4 acc[2][2] = {};

#define T_LOAD(ch) { const int ib_ = (ch) * 64; \
    _Pragma("unroll") for (int r = 0; r < 16; ++r) { \
        const int il = ig * 16 + r; \
        rA[r] = GHn[(size_t)(ib_ + il) * 256 + o0 + cA]; \
        rB[r] = Mn[(size_t)(ib_ + il) * 256 + p0 + cA]; } }

    T_LOAD(0);
    for (int ch = 0; ch < 16; ++ch) {
        __syncthreads();
        #pragma unroll
        for (int r = 0; r < 16; ++r) {
            const int il = ig * 16 + r;
            sA[cA * KP + il] = rA[r];
            sB[cA * KP + il] = f2b(rB[r]);
        }
        __syncthreads();
        if (ch < 15) T_LOAD(ch + 1);            // overlaps MFMA phase
        #pragma unroll
        for (int kb = 0; kb < 2; ++kb) {
            const int ko = kb * 32 + g4 * 8;
            bf16x8 fa[2], fb[2];
            #pragma unroll
            for (int fm = 0; fm < 2; ++fm)
                fa[fm] = ld_frag(sA + (wr*32 + fm*16 + t16) * KP + ko);
            #pragma unroll
            for (int fn = 0; fn < 2; ++fn)
                fb[fn] = ld_frag(sB + (wc*32 + fn*16 + t16) * KP + ko);
            #pragma unroll
            for (int fm = 0; fm < 2; ++fm)
                #pragma unroll
                for (int fn = 0; fn < 2; ++fn)
                    acc[fm][fn] = __builtin_amdgcn_mfma_f32_16x16x32_bf16(fa[fm], fb[fn], acc[fm][fn], 0, 0, 0);
        }
    }
    const float* bs = BS + n * DOUT;
    u16t* TTn = TT + ((size_t)n << 16);
    #pragma unroll
    for (int fm = 0; fm < 2; ++fm)
        #pragma unroll
        for (int fn = 0; fn < 2; ++fn) {
            const int p = p0 + wc*32 + fn*16 + t16;
            #pragma unroll
            for (int r = 0; r < 4; ++r) {
                const int o = o0 + wr*32 + fm*16 + g4*4 + r;
                TTn[o * 256 + p] = f2b(acc[fm][fn][r] * bs[o]);
            }
        }
}

// ============================================================
// G2 (k_Abuild): A[i][o] = M + EPS*( sum_p M[i][p]*TT[o][p] - b_o*GH[i][o] )
// block tile 64i x 64o, K=256 (4 chunks). grid 4096 = (64 tiles x 64 n).
// ============================================================
__global__ __launch_bounds__(256, 4) void k_Abuild(
    const float* __restrict__ M, const u16t* __restrict__ GH,
    const float* __restrict__ BS, const u16t* __restrict__ TT,
    u16t* __restrict__ AH)
{
    __shared__ u16t sA[64 * KP];   // [i][p]
    __shared__ u16t sB[64 * KP];   // [o][p]
    const int bid = blockIdx.x;
    const int n = bid & 63;
    const int tile = bid >> 6;                  // 0..63
    const int i0 = (tile & 15) * 64, o0 = (tile >> 4) * 64;
    const int t = threadIdx.x, lane = t & 63, w = t >> 6;
    const int wr = w >> 1, wc = w & 1, t16 = lane & 15, g4 = lane >> 4;
    const float* Mn = M + ((size_t)n << 18);
    const u16t* GHn = GH + ((size_t)n << 18);
    const u16t* TTn = TT + ((size_t)n << 16);
    float4 rMa[4];
    uint4  rTb[2];
    f32x4 acc[2][2] = {};

#define AB_LOAD(ch) { const int pb_ = (ch) * 64; \
    _Pragma("unroll") for (int j = 0; j < 4; ++j) { \
        const int s = j * 256 + t, row = s >> 4, c4 = (s & 15) * 4; \
        rMa[j] = *(const float4*)(Mn + (size_t)(i0 + row) * 256 + pb_ + c4); } \
    _Pragma("unroll") for (int j = 0; j < 2; ++j) { \
        const int s = j * 256 + t, row = s >> 3, c8 = (s & 7) * 8; \
        rTb[j] = *(const uint4*)(TTn + (size_t)(o0 + row) * 256 + pb_ + c8); } }

    AB_LOAD(0);
    for (int ch = 0; ch < 4; ++ch) {
        __syncthreads();
        #pragma unroll
        for (int j = 0; j < 4; ++j) {
            const int s = j * 256 + t, row = s >> 4, c4 = (s & 15) * 4;
            const float4 v = rMa[j];
            ushort4 h = { f2b(v.x), f2b(v.y), f2b(v.z), f2b(v.w) };
            *(ushort4*)(sA + row * KP + c4) = h;
        }
        #pragma unroll
        for (int j = 0; j < 2; ++j) {
            const int s = j * 256 + t, row = s >> 3, c8 = (s & 7) * 8;
            st8(sB + row * KP + c8,     rTb[j].x, rTb[j].y);
            st8(sB + row * KP + c8 + 4, rTb[j].z, rTb[j].w);
        }
        __syncthreads();
        if (ch < 3) AB_LOAD(ch + 1);
        #pragma unroll
        for (int kb = 0; kb < 2; ++kb) {
            const int ko = kb * 32 + g4 * 8;
            bf16x8 fa[2], fb[2];
            #pragma unroll
            for (int fm = 0; fm < 2; ++fm)
                fa[fm] = ld_frag(sA + (wr*32 + fm*16 + t16) * KP + ko);
            #pragma unroll
            for (int fn = 0; fn < 2; ++fn)
                fb[fn] = ld_frag(sB + (wc*32 + fn*16 + t16) * KP + ko);
            #pragma unroll
            for (int fm = 0; fm < 2; ++fm)
                #pragma unroll
                for (int fn = 0; fn < 2; ++fn)
                    acc[fm][fn] = __builtin_amdgcn_mfma_f32_16x16x32_bf16(fa[fm], fb[fn], acc[fm][fn], 0, 0, 0);
        }
    }
    const float* bs = BS + n * DOUT;
    u16t* AHn = AH + ((size_t)n << 18);
    #pragma unroll
    for (int fm = 0; fm < 2; ++fm)
        #pragma unroll
        for (int fn = 0; fn < 2; ++fn) {
            const int o = o0 + wc*32 + fn*16 + t16;
            const float bo = bs[o];
            #pragma unroll
            for (int r = 0; r < 4; ++r) {
                const int i = i0 + wr*32 + fm*16 + g4*4 + r;
                const size_t idx = (size_t)i * 256 + o;
                const float Aval = Mn[idx] + EPS * (acc[fm][fn][r] - bo * b2f(GHn[idx]));
                AHn[idx] = f2b(Aval);
            }
        }
}

// ============================================================
// G3 (k_E): EH[p][o] = bf16( 0.5*(A^T A - I) ). block tile 64p x 64o,
// K=1024. grid 1024 = (16 tiles x 64 n). Diag tiles stage once.
// ============================================================
__global__ __launch_bounds__(256, 4) void k_E(
    const u16t* __restrict__ AH, u16t* __restrict__ EH)
{
    __shared__ u16t sA[64 * KP];   // [p][i]
    __shared__ u16t sB[64 * KP];   // [o][i]
    const int bid = blockIdx.x;
    const int n = bid & 63;
    const int tile = bid >> 6;                  // 0..15
    const int p0 = (tile >> 2) * 64, o0 = (tile & 3) * 64;
    const bool diag = (p0 == o0);
    const int t = threadIdx.x, lane = t & 63, w = t >> 6;
    const int wr = w >> 1, wc = w & 1, t16 = lane & 15, g4 = lane >> 4;
    const int cA = t & 63, ig = t >> 6;
    const u16t* AHn = AH + ((size_t)n << 18);
    u16t rA[16], rB[16];
    f32x4 acc[2][2] = {};

#define E_LOAD(ch) { const int ib_ = (ch) * 64; \
    _Pragma("unroll") for (int r = 0; r < 16; ++r) { \
        const int il = ig * 16 + r; \
        const u16t* src = AHn + (size_t)(ib_ + il) * 256; \
        rA[r] = src[p0 + cA]; \
        if (!diag) rB[r] = src[o0 + cA]; } }

    E_LOAD(0);
    for (int ch = 0; ch < 16; ++ch) {
        __syncthreads();
        #pragma unroll
        for (int r = 0; r < 16; ++r) {
            const int il = ig * 16 + r;
            sA[cA * KP + il] = rA[r];
            if (!diag) sB[cA * KP + il] = rB[r];
        }
        __syncthreads();
        if (ch < 15) E_LOAD(ch + 1);
        const u16t* sBr = diag ? sA : sB;
        #pragma unroll
        for (int kb = 0; kb < 2; ++kb) {
            const int ko = kb * 32 + g4 * 8;
            bf16x8 fa[2], fb[2];
            #pragma unroll
            for (int fm = 0; fm < 2; ++fm)
                fa[fm] = ld_frag(sA + (wr*32 + fm*16 + t16) * KP + ko);
            #pragma unroll
            for (int fn = 0; fn < 2; ++fn)
                fb[fn] = ld_frag(sBr + (wc*32 + fn*16 + t16) * KP + ko);
            #pragma unroll
            for (int fm = 0; fm < 2; ++fm)
                #pragma unroll
                for (int fn = 0; fn < 2; ++fn)
                    acc[fm][fn] = __builtin_amdgcn_mfma_f32_16x16x32_bf16(fa[fm], fb[fn], acc[fm][fn], 0, 0, 0);
        }
    }
    u16t* EHn = EH + ((size_t)n << 16);
    #pragma unroll
    for (int fm = 0; fm < 2; ++fm)
        #pragma unroll
        for (int fn = 0; fn < 2; ++fn) {
            const int o = o0 + wc*32 + fn*16 + t16;
            #pragma unroll
            for (int r = 0; r < 4; ++r) {
                const int p = p0 + wr*32 + fm*16 + g4*4 + r;
                const float v = 0.5f * acc[fm][fn][r] - (p == o ? 0.5f : 0.f);
                EHn[p * 256 + o] = f2b(v);
            }
        }
}

// ============================================================
// G4 (k_Mnew): Mnew[i][o] = b2f(AH[i][o]) - sum_p AH[i][p]*EH[o][p] (EH sym)
// block tile 64i x 64o, K=256 (4 chunks). grid 4096.
// ============================================================
__global__ __launch_bounds__(256, 4) void k_Mnew(
    const u16t* __restrict__ AH, const u16t* __restrict__ EH,
    float* __restrict__ out)
{
    __shared__ u16t sA[64 * KP];   // [i][p]
    __shared__ u16t sB[64 * KP];   // [o][p]
    const int bid = blockIdx.x;
    const int n = bid & 63;
    const int tile = bid >> 6;                  // 0..63
    const int i0 = (tile & 15) * 64, o0 = (tile >> 4) * 64;
    const int t = threadIdx.x, lane = t & 63, w = t >> 6;
    const int wr = w >> 1, wc = w & 1, t16 = lane & 15, g4 = lane >> 4;
    const u16t* AHn = AH + ((size_t)n << 18);
    const u16t* EHn = EH + ((size_t)n << 16);
    uint4 rAa[2], rEb[2];
    f32x4 acc[2][2] = {};

#define MN_LOAD(ch) { const int pb_ = (ch) * 64; \
    _Pragma("unroll") for (int j = 0; j < 2; ++j) { \
        const int s = j * 256 + t, row = s >> 3, c8 = (s & 7) * 8; \
        rAa[j] = *(const uint4*)(AHn + (size_t)(i0 + row) * 256 + pb_ + c8); \
        rEb[j] = *(const uint4*)(EHn + (size_t)(o0 + row) * 256 + pb_ + c8); } }

    MN_LOAD(0);
    for (int ch = 0; ch < 4; ++ch) {
        __syncthreads();
        #pragma unroll
        for (int j = 0; j < 2; ++j) {
            const int s = j * 256 + t, row = s >> 3, c8 = (s & 7) * 8;
            st8(sA + row * KP + c8,     rAa[j].x, rAa[j].y);
            st8(sA + row * KP + c8 + 4, rAa[j].z, rAa[j].w);
            st8(sB + row * KP + c8,     rEb[j].x, rEb[j].y);
            st8(sB + row * KP + c8 + 4, rEb[j].z, rEb[j].w);
        }
        __syncthreads();
        if (ch < 3) MN_LOAD(ch + 1);
        #pragma unroll
        for (int kb = 0; kb < 2; ++kb) {
            const int ko = kb * 32 + g4 * 8;
            bf16x8 fa[2], fb[2];
            #pragma unroll
            for (int fm = 0; fm < 2; ++fm)
                fa[fm] = ld_frag(sA + (wr*32 + fm*16 + t16) * KP + ko);
            #pragma unroll
            for (int fn = 0; fn < 2; ++fn)
                fb[fn] = ld_frag(sB + (wc*32 + fn*16 + t16) * KP + ko);
            #pragma unroll
            for (int fm = 0; fm < 2; ++fm)
                #pragma unroll
                for (int fn = 0; fn < 2; ++fn)
                    acc[fm][fn] = __builtin_amdgcn_mfma_f32_16x16x32_bf16(fa[fm], fb[fn], acc[fm][fn], 0, 0, 0);
        }
    }
    float* outn = out + ((size_t)n << 18);
    #pragma unroll
    for (int fm = 0; fm < 2; ++fm)
        #pragma unroll
        for (int fn = 0; fn < 2; ++fn) {
            const int o = o0 + wc*32 + fn*16 + t16;
            #pragma unroll
            for (int r = 0; r < 4; ++r) {
                const int i = i0 + wr*32 + fm*16 + g4*4 + r;
                const size_t idx = (size_t)i * 256 + o;
                outn[idx] = b2f(AHn[idx]) - acc[fm][fn][r];
            }
        }
}

extern "C" void kernel_launch(void* const* d_in, const int* in_sizes, int n_in,
                              void* d_out, int out_size, void* d_ws, size_t ws_size,
                              hipStream_t stream) {
    const float* grad  = (const float*)d_in[0];
    const float* M     = (const float*)d_in[1];
    const float* state = (const float*)d_in[2];
    const float* L0    = (const float*)d_in[3];
    const float* R0    = (const float*)d_in[4];
    float* out = (float*)d_out;
    char* wsb = (char*)d_ws;

    // region map (~80.1 MB; <= 85 MB proven safe in R1):
    u16t* GH  = (u16t*)(wsb);                          // [0,32MB)   GH[n][i][o]
    u16t* AH  = (u16t*)(wsb + ((size_t)32 << 20));     // [32,64MB)  AH[n][i][o]
    u16t* TT  = (u16t*)(wsb + ((size_t)64 << 20));     // [64,72MB)  TT[n][o][p]
    u16t* EH  = TT;                                    // EH aliases TT (dead after k_Abuild)
    float* CP = (float*)(wsb + ((size_t)72 << 20));    // [72,80MB)  CP[n][128][256]
    float* BS = (float*)(wsb + ((size_t)80 << 20));    // 64KB

    k_prep  <<<2048, 256, 0, stream>>>(grad, L0, out, GH, CP);
    k_cols  <<<64,   256, 0, stream>>>(R0, state, out, BS, CP);
    k_T     <<<1024, 256, 0, stream>>>(GH, M, BS, TT);
    k_Abuild<<<4096, 256, 0, stream>>>(M, GH, BS, TT, AH);
    k_E     <<<1024, 256, 0, stream>>>(AH, EH);
    k_Mnew  <<<4096, 256, 0, stream>>>(AH, EH, out);
}

// Round 8
// 166.862 us; speedup vs baseline: 1.1312x; 1.1312x over previous
//
#include <hip/hip_runtime.h>

typedef unsigned short u16t;
typedef unsigned int   u32t;
typedef __bf16 bf16x8 __attribute__((ext_vector_type(8)));
typedef float  f32x4  __attribute__((ext_vector_type(4)));

#define NB   64
#define DIN  1024
#define DOUT 256
#define EPS  1e-4f   // LR*LR
#define KP   68      // LDS row stride in u16 (34 dw == 2 mod 32)

#define OUT_STATE (NB*DIN*DOUT)
#define OUT_LL    (OUT_STATE + 1)
#define OUT_RR    (OUT_LL + NB*DIN)

__device__ __forceinline__ u16t f2b(float x) {
    u32t u = __builtin_bit_cast(u32t, x);
    u += 0x7FFFu + ((u >> 16) & 1u);          // RTNE
    return (u16t)(u >> 16);
}
__device__ __forceinline__ float b2f(u16t h) {
    return __builtin_bit_cast(float, ((u32t)h) << 16);
}
__device__ __forceinline__ bf16x8 ld_frag(const u16t* p) {
    uint2 lo = *(const uint2*)(p);
    uint2 hi = *(const uint2*)(p + 4);
    union { uint4 u; bf16x8 v; } x;
    x.u = make_uint4(lo.x, lo.y, hi.x, hi.y);
    return x.v;
}
__device__ __forceinline__ void wr8(u16t* dst, uint4 v, int i) {
    // scatter 8 u16 of one uint4 into transposed LDS: dst[(c)*KP + i]
    const u16t* s = (const u16t*)&v;
    #pragma unroll
    for (int c = 0; c < 8; ++c) dst[c * KP + i] = s[c];
}

// ============================================================
// K1: grad row moments -> ll (out), GH = bf16(a*grad), col partials CP.
// grid 2048 = (32 chunks x 64 n), block 256.
// ============================================================
__global__ __launch_bounds__(256) void k_prep(
    const float* __restrict__ grad, const float* __restrict__ L0,
    float* __restrict__ out, u16t* __restrict__ GH, float* __restrict__ CP)
{
    const int bid = blockIdx.x;
    const int n = bid & 63;
    const int chunk = bid >> 6;
    const int wave = threadIdx.x >> 6, lane = threadIdx.x & 63;
    const float* gb = grad + ((size_t)n << 18);
    u16t* GHn = GH + ((size_t)n << 18);

    float4 cacc = {0.f, 0.f, 0.f, 0.f};
    const int i0 = chunk * 32 + wave * 8;
    #pragma unroll
    for (int r = 0; r < 8; ++r) {
        const int i = i0 + r;
        const float4 v = *(const float4*)(gb + (size_t)i * 256 + lane * 4);
        float s = v.x*v.x + v.y*v.y + v.z*v.z + v.w*v.w;
        cacc.x += v.x*v.x; cacc.y += v.y*v.y; cacc.z += v.z*v.z; cacc.w += v.w*v.w;
        #pragma unroll
        for (int off = 32; off; off >>= 1) s += __shfl_xor(s, off);
        const float l0 = L0[n * DIN + i];
        const float ll = fmaxf(l0, 0.5f * l0 + s * (0.5f / DOUT));
        const float a  = rsqrtf(sqrtf(ll));
        ushort4 g4v = { f2b(v.x*a), f2b(v.y*a), f2b(v.z*a), f2b(v.w*a) };
        *(ushort4*)(GHn + (size_t)i * 256 + lane * 4) = g4v;
        if (lane == 0) out[OUT_LL + n * DIN + i] = ll;
    }
    const int slot = chunk * 4 + wave;
    *(float4*)(CP + ((size_t)(n * 128 + slot)) * 256 + lane * 4) = cacc;
}

// ============================================================
// K2: reduce 128 col partials -> rr (out), BS = rr^-1/4 ; copy state
// ============================================================
__global__ __launch_bounds__(256) void k_cols(
    const float* __restrict__ R0, const float* __restrict__ state,
    float* __restrict__ out, float* __restrict__ BS, const float* __restrict__ CP)
{
    const int n = blockIdx.x, o = threadIdx.x;
    const float* cp = CP + (size_t)n * 128 * 256 + o;
    float s = 0.f;
    #pragma unroll 8
    for (int k = 0; k < 128; ++k) s += cp[k * 256];
    const float r0 = R0[n * DOUT + o];
    const float rr = fmaxf(r0, 0.5f * r0 + s * (0.5f / DIN));
    out[OUT_RR + n * DOUT + o] = rr;
    BS[n * DOUT + o] = rsqrtf(sqrtf(rr));
    if (n == 0 && o == 0) out[OUT_STATE] = state[0];
}

// ============================================================
// G1 (k_T): TT[o][p] = b[o] * sum_i GH[i][o] * M[i][p]
// tile 128o x 64p, BK=64. grid 512 = (8 tiles x 64 n). 4 waves 2x2.
// Vector global loads + conflict-free transpose LDS writes (i in lane LSBs).
// ============================================================
__global__ __launch_bounds__(256, 3) void k_T(
    const u16t* __restrict__ GH, const float* __restrict__ M,
    const float* __restrict__ BS, u16t* __restrict__ TT)
{
    __shared__ u16t sA[128 * KP];   // [o][i]
    __shared__ u16t sB[64 * KP];    // [p][i]
    const int bid = blockIdx.x;
    const int n = bid & 63;
    const int tile = bid >> 6;                  // 0..7
    const int o0 = (tile & 1) * 128, p0 = (tile >> 1) * 64;
    const int t = threadIdx.x, lane = t & 63, w = t >> 6;
    const int wr = w >> 1, wc = w & 1, t16 = lane & 15, g4 = lane >> 4;
    const u16t* GHn = GH + ((size_t)n << 18);
    const float* Mn = M + ((size_t)n << 18);
    uint4  rA[4];
    float4 rB[4];
    f32x4 acc[4][2] = {};

#define T_LOAD(ch) { const int ib_ = (ch) * 64; \
    _Pragma("unroll") for (int j = 0; j < 4; ++j) { \
        const int s = j * 256 + t; \
        const int ia = (s & 31) | ((s >> 9) << 5), c8 = ((s >> 5) & 15) * 8; \
        rA[j] = *(const uint4*)(GHn + (size_t)(ib_ + ia) * 256 + o0 + c8); \
        const int ibf = (s & 31) | ((s >> 9) << 5), c4 = ((s >> 5) & 15) * 4; \
        rB[j] = *(const float4*)(Mn + (size_t)(ib_ + ibf) * 256 + p0 + c4); } }

    T_LOAD(0);
    for (int ch = 0; ch < 16; ++ch) {
        __syncthreads();
        #pragma unroll
        for (int j = 0; j < 4; ++j) {
            const int s = j * 256 + t;
            const int ia = (s & 31) | ((s >> 9) << 5), c8 = ((s >> 5) & 15) * 8;
            wr8(sA + c8 * KP, rA[j], ia);
            const int c4 = ((s >> 5) & 15) * 4;
            const float4 v = rB[j];
            sB[(c4+0)*KP + ia] = f2b(v.x);
            sB[(c4+1)*KP + ia] = f2b(v.y);
            sB[(c4+2)*KP + ia] = f2b(v.z);
            sB[(c4+3)*KP + ia] = f2b(v.w);
        }
        __syncthreads();
        if (ch < 15) T_LOAD(ch + 1);            // overlaps MFMA phase
        #pragma unroll
        for (int kb = 0; kb < 2; ++kb) {
            const int ko = kb * 32 + g4 * 8;
            bf16x8 fa[4], fb[2];
            #pragma unroll
            for (int fm = 0; fm < 4; ++fm)
                fa[fm] = ld_frag(sA + (wr*64 + fm*16 + t16) * KP + ko);
            #pragma unroll
            for (int fn = 0; fn < 2; ++fn)
                fb[fn] = ld_frag(sB + (wc*32 + fn*16 + t16) * KP + ko);
            #pragma unroll
            for (int fm = 0; fm < 4; ++fm)
                #pragma unroll
                for (int fn = 0; fn < 2; ++fn)
                    acc[fm][fn] = __builtin_amdgcn_mfma_f32_16x16x32_bf16(fa[fm], fb[fn], acc[fm][fn], 0, 0, 0);
        }
    }
    const float* bs = BS + n * DOUT;
    u16t* TTn = TT + ((size_t)n << 16);
    #pragma unroll
    for (int fm = 0; fm < 4; ++fm)
        #pragma unroll
        for (int fn = 0; fn < 2; ++fn) {
            const int p = p0 + wc*32 + fn*16 + t16;
            #pragma unroll
            for (int r = 0; r < 4; ++r) {
                const int o = o0 + wr*64 + fm*16 + g4*4 + r;
                TTn[o * 256 + p] = f2b(acc[fm][fn][r] * bs[o]);
            }
        }
}

// ============================================================
// G3 (k_E): EH[p][o] = bf16( 0.5*(A^T A - I) ). tile 128p x 64o, BK=64.
// grid 512 = (8 tiles x 64 n). Same staging scheme as k_T (both bf16).
// ============================================================
__global__ __launch_bounds__(256, 3) void k_E(
    const u16t* __restrict__ AH, u16t* __restrict__ EH)
{
    __shared__ u16t sA[128 * KP];   // [p][i]
    __shared__ u16t sB[64 * KP];    // [o][i]
    const int bid = blockIdx.x;
    const int n = bid & 63;
    const int tile = bid >> 6;                  // 0..7
    const int p0 = (tile & 1) * 128, o0 = (tile >> 1) * 64;
    const int t = threadIdx.x, lane = t & 63, w = t >> 6;
    const int wr = w >> 1, wc = w & 1, t16 = lane & 15, g4 = lane >> 4;
    const u16t* AHn = AH + ((size_t)n << 18);
    uint4 rA[4], rB[2];
    f32x4 acc[4][2] = {};

#define E_LOAD(ch) { const int ib_ = (ch) * 64; \
    _Pragma("unroll") for (int j = 0; j < 4; ++j) { \
        const int s = j * 256 + t; \
        const int ia = (s & 31) | ((s >> 9) << 5), c8 = ((s >> 5) & 15) * 8; \
        rA[j] = *(const uint4*)(AHn + (size_t)(ib_ + ia) * 256 + p0 + c8); } \
    _Pragma("unroll") for (int j = 0; j < 2; ++j) { \
        const int s = j * 256 + t; \
        const int ia = (s & 31) | ((s >> 8) << 5), c8 = ((s >> 5) & 7) * 8; \
        rB[j] = *(const uint4*)(AHn + (size_t)(ib_ + ia) * 256 + o0 + c8); } }

    E_LOAD(0);
    for (int ch = 0; ch < 16; ++ch) {
        __syncthreads();
        #pragma unroll
        for (int j = 0; j < 4; ++j) {
            const int s = j * 256 + t;
            const int ia = (s & 31) | ((s >> 9) << 5), c8 = ((s >> 5) & 15) * 8;
            wr8(sA + c8 * KP, rA[j], ia);
        }
        #pragma unroll
        for (int j = 0; j < 2; ++j) {
            const int s = j * 256 + t;
            const int ia = (s & 31) | ((s >> 8) << 5), c8 = ((s >> 5) & 7) * 8;
            wr8(sB + c8 * KP, rB[j], ia);
        }
        __syncthreads();
        if (ch < 15) E_LOAD(ch + 1);
        #pragma unroll
        for (int kb = 0; kb < 2; ++kb) {
            const int ko = kb * 32 + g4 * 8;
            bf16x8 fa[4], fb[2];
            #pragma unroll
            for (int fm = 0; fm < 4; ++fm)
                fa[fm] = ld_frag(sA + (wr*64 + fm*16 + t16) * KP + ko);
            #pragma unroll
            for (int fn = 0; fn < 2; ++fn)
                fb[fn] = ld_frag(sB + (wc*32 + fn*16 + t16) * KP + ko);
            #pragma unroll
            for (int fm = 0; fm < 4; ++fm)
                #pragma unroll
                for (int fn = 0; fn < 2; ++fn)
                    acc[fm][fn] = __builtin_amdgcn_mfma_f32_16x16x32_bf16(fa[fm], fb[fn], acc[fm][fn], 0, 0, 0);
        }
    }
    u16t* EHn = EH + ((size_t)n << 16);
    #pragma unroll
    for (int fm = 0; fm < 4; ++fm)
        #pragma unroll
        for (int fn = 0; fn < 2; ++fn) {
            const int o = o0 + wc*32 + fn*16 + t16;
            #pragma unroll
            for (int r = 0; r < 4; ++r) {
                const int p = p0 + wr*64 + fm*16 + g4*4 + r;
                const float v = 0.5f * acc[fm][fn][r] - (p == o ? 0.5f : 0.f);
                EHn[p * 256 + o] = f2b(v);
            }
        }
}

// ============================================================
// G2 (k_Abuild): A[i][o] = M + EPS*( sum_p M[i][p]*TT[o][p] - b_o*GH[i][o] )
// tile 128i x 64o, BK=64 (4 chunks). grid 2048 = (32 tiles x 64 n).
// ============================================================
__global__ __launch_bounds__(256, 3) void k_Abuild(
    const float* __restrict__ M, const u16t* __restrict__ GH,
    const float* __restrict__ BS, const u16t* __restrict__ TT,
    u16t* __restrict__ AH)
{
    __shared__ u16t sA[128 * KP];   // [i][p]
    __shared__ u16t sB[64 * KP];    // [o][p]
    const int bid = blockIdx.x;
    const int n = bid & 63;
    const int tile = bid >> 6;                  // 0..31
    const int i0 = (tile & 7) * 128, o0 = (tile >> 3) * 64;
    const int t = threadIdx.x, lane = t & 63, w = t >> 6;
    const int wr = w >> 1, wc = w & 1, t16 = lane & 15, g4 = lane >> 4;
    const float* Mn = M + ((size_t)n << 18);
    const u16t* GHn = GH + ((size_t)n << 18);
    const u16t* TTn = TT + ((size_t)n << 16);
    float4 rMa[8];
    uint4  rTb[2];
    f32x4 acc[4][2] = {};

#define AB_LOAD(ch) { const int pb_ = (ch) * 64; \
    _Pragma("unroll") for (int j = 0; j < 8; ++j) { \
        const int s = j * 256 + t, row = s >> 4, c4 = (s & 15) * 4; \
        rMa[j] = *(const float4*)(Mn + (size_t)(i0 + row) * 256 + pb_ + c4); } \
    _Pragma("unroll") for (int j = 0; j < 2; ++j) { \
        const int s = j * 256 + t, row = s >> 3, c8 = (s & 7) * 8; \
        rTb[j] = *(const uint4*)(TTn + (size_t)(o0 + row) * 256 + pb_ + c8); } }

    AB_LOAD(0);
    for (int ch = 0; ch < 4; ++ch) {
        __syncthreads();
        #pragma unroll
        for (int j = 0; j < 8; ++j) {
            const int s = j * 256 + t, row = s >> 4, c4 = (s & 15) * 4;
            const float4 v = rMa[j];
            ushort4 h = { f2b(v.x), f2b(v.y), f2b(v.z), f2b(v.w) };
            *(ushort4*)(sA + row * KP + c4) = h;
        }
        #pragma unroll
        for (int j = 0; j < 2; ++j) {
            const int s = j * 256 + t, row = s >> 3, c8 = (s & 7) * 8;
            *(uint2*)(sB + row * KP + c8)     = make_uint2(rTb[j].x, rTb[j].y);
            *(uint2*)(sB + row * KP + c8 + 4) = make_uint2(rTb[j].z, rTb[j].w);
        }
        __syncthreads();
        if (ch < 3) AB_LOAD(ch + 1);
        #pragma unroll
        for (int kb = 0; kb < 2; ++kb) {
            const int ko = kb * 32 + g4 * 8;
            bf16x8 fa[4], fb[2];
            #pragma unroll
            for (int fm = 0; fm < 4; ++fm)
                fa[fm] = ld_frag(sA + (wr*64 + fm*16 + t16) * KP + ko);
            #pragma unroll
            for (int fn = 0; fn < 2; ++fn)
                fb[fn] = ld_frag(sB + (wc*32 + fn*16 + t16) * KP + ko);
            #pragma unroll
            for (int fm = 0; fm < 4; ++fm)
                #pragma unroll
                for (int fn = 0; fn < 2; ++fn)
                    acc[fm][fn] = __builtin_amdgcn_mfma_f32_16x16x32_bf16(fa[fm], fb[fn], acc[fm][fn], 0, 0, 0);
        }
    }
    const float* bs = BS + n * DOUT;
    u16t* AHn = AH + ((size_t)n << 18);
    #pragma unroll
    for (int fm = 0; fm < 4; ++fm)
        #pragma unroll
        for (int fn = 0; fn < 2; ++fn) {
            const int o = o0 + wc*32 + fn*16 + t16;
            const float bo = bs[o];
            #pragma unroll
            for (int r = 0; r < 4; ++r) {
                const int i = i0 + wr*64 + fm*16 + g4*4 + r;
                const size_t idx = (size_t)i * 256 + o;
                const float Aval = Mn[idx] + EPS * (acc[fm][fn][r] - bo * b2f(GHn[idx]));
                AHn[idx] = f2b(Aval);
            }
        }
}

// ============================================================
// G4 (k_Mnew): Mnew[i][o] = b2f(AH[i][o]) - sum_p AH[i][p]*EH[o][p] (EH sym)
// tile 128i x 64o, BK=64 (4 chunks). grid 2048.
// ============================================================
__global__ __launch_bounds__(256, 3) void k_Mnew(
    const u16t* __restrict__ AH, const u16t* __restrict__ EH,
    float* __restrict__ out)
{
    __shared__ u16t sA[128 * KP];   // [i][p]
    __shared__ u16t sB[64 * KP];    // [o][p]
    const int bid = blockIdx.x;
    const int n = bid & 63;
    const int tile = bid >> 6;                  // 0..31
    const int i0 = (tile & 7) * 128, o0 = (tile >> 3) * 64;
    const int t = threadIdx.x, lane = t & 63, w = t >> 6;
    const int wr = w >> 1, wc = w & 1, t16 = lane & 15, g4 = lane >> 4;
    const u16t* AHn = AH + ((size_t)n << 18);
    const u16t* EHn = EH + ((size_t)n << 16);
    uint4 rAa[4], rEb[2];
    f32x4 acc[4][2] = {};

#define MN_LOAD(ch) { const int pb_ = (ch) * 64; \
    _Pragma("unroll") for (int j = 0; j < 4; ++j) { \
        const int s = j * 256 + t, row = s >> 3, c8 = (s & 7) * 8; \
        rAa[j] = *(const uint4*)(AHn + (size_t)(i0 + row) * 256 + pb_ + c8); } \
    _Pragma("unroll") for (int j = 0; j < 2; ++j) { \
        const int s = j * 256 + t, row = s >> 3, c8 = (s & 7) * 8; \
        rEb[j] = *(const uint4*)(EHn + (size_t)(o0 + row) * 256 + pb_ + c8); } }

    MN_LOAD(0);
    for (int ch = 0; ch < 4; ++ch) {
        __syncthreads();
        #pragma unroll
        for (int j = 0; j < 4; ++j) {
            const int s = j * 256 + t, row = s >> 3, c8 = (s & 7) * 8;
            *(uint2*)(sA + row * KP + c8)     = make_uint2(rAa[j].x, rAa[j].y);
            *(uint2*)(sA + row * KP + c8 + 4) = make_uint2(rAa[j].z, rAa[j].w);
        }
        #pragma unroll
        for (int j = 0; j < 2; ++j) {
            const int s = j * 256 + t, row = s >> 3, c8 = (s & 7) * 8;
            *(uint2*)(sB + row * KP + c8)     = make_uint2(rEb[j].x, rEb[j].y);
            *(uint2*)(sB + row * KP + c8 + 4) = make_uint2(rEb[j].z, rEb[j].w);
        }
        __syncthreads();
        if (ch < 3) MN_LOAD(ch + 1);
        #pragma unroll
        for (int kb = 0; kb < 2; ++kb) {
            const int ko = kb * 32 + g4 * 8;
            bf16x8 fa[4], fb[2];
            #pragma unroll
            for (int fm = 0; fm < 4; ++fm)
                fa[fm] = ld_frag(sA + (wr*64 + fm*16 + t16) * KP + ko);
            #pragma unroll
            for (int fn = 0; fn < 2; ++fn)
                fb[fn] = ld_frag(sB + (wc*32 + fn*16 + t16) * KP + ko);
            #pragma unroll
            for (int fm = 0; fm < 4; ++fm)
                #pragma unroll
                for (int fn = 0; fn < 2; ++fn)
                    acc[fm][fn] = __builtin_amdgcn_mfma_f32_16x16x32_bf16(fa[fm], fb[fn], acc[fm][fn], 0, 0, 0);
        }
    }
    float* outn = out + ((size_t)n << 18);
    #pragma unroll
    for (int fm = 0; fm < 4; ++fm)
        #pragma unroll
        for (int fn = 0; fn < 2; ++fn) {
            const int o = o0 + wc*32 + fn*16 + t16;
            #pragma unroll
            for (int r = 0; r < 4; ++r) {
                const int i = i0 + wr*64 + fm*16 + g4*4 + r;
                const size_t idx = (size_t)i * 256 + o;
                outn[idx] = b2f(AHn[idx]) - acc[fm][fn][r];
            }
        }
}

extern "C" void kernel_launch(void* const* d_in, const int* in_sizes, int n_in,
                              void* d_out, int out_size, void* d_ws, size_t ws_size,
                              hipStream_t stream) {
    const float* grad  = (const float*)d_in[0];
    const float* M     = (const float*)d_in[1];
    const float* state = (const float*)d_in[2];
    const float* L0    = (const float*)d_in[3];
    const float* R0    = (const float*)d_in[4];
    float* out = (float*)d_out;
    char* wsb = (char*)d_ws;

    // region map (~80.1 MB; <= 85 MB proven safe in R1):
    u16t* GH  = (u16t*)(wsb);                          // [0,32MB)   GH[n][i][o]
    u16t* AH  = (u16t*)(wsb + ((size_t)32 << 20));     // [32,64MB)  AH[n][i][o]
    u16t* TT  = (u16t*)(wsb + ((size_t)64 << 20));     // [64,72MB)  TT[n][o][p]
    u16t* EH  = TT;                                    // EH aliases TT (dead after k_Abuild)
    float* CP = (float*)(wsb + ((size_t)72 << 20));    // [72,80MB)  CP[n][128][256]
    float* BS = (float*)(wsb + ((size_t)80 << 20));    // 64KB

    k_prep  <<<2048, 256, 0, stream>>>(grad, L0, out, GH, CP);
    k_cols  <<<64,   256, 0, stream>>>(R0, state, out, BS, CP);
    k_T     <<<512,  256, 0, stream>>>(GH, M, BS, TT);
    k_Abuild<<<2048, 256, 0, stream>>>(M, GH, BS, TT, AH);
    k_E     <<<512,  256, 0, stream>>>(AH, EH);
    k_Mnew  <<<2048, 256, 0, stream>>>(AH, EH, out);
}

// Round 9
// 102.955 us; speedup vs baseline: 1.8334x; 1.6207x over previous
//
#include <hip/hip_runtime.h>

typedef unsigned short u16t;
typedef unsigned int   u32t;
typedef __bf16 bf16x8 __attribute__((ext_vector_type(8)));
typedef float  f32x4  __attribute__((ext_vector_type(4)));

#define NB   64
#define DIN  1024
#define DOUT 256
#define EPS  1e-4f   // LR*LR
#define KP   68      // LDS row stride in u16 (34 dw == 2 mod 32)

#define OUT_STATE (NB*DIN*DOUT)
#define OUT_LL    (OUT_STATE + 1)
#define OUT_RR    (OUT_LL + NB*DIN)

__device__ __forceinline__ u16t f2b(float x) {
    u32t u = __builtin_bit_cast(u32t, x);
    u += 0x7FFFu + ((u >> 16) & 1u);          // RTNE
    return (u16t)(u >> 16);
}
__device__ __forceinline__ float b2f(u16t h) {
    return __builtin_bit_cast(float, ((u32t)h) << 16);
}
__device__ __forceinline__ bf16x8 ld_frag(const u16t* p) {
    uint2 lo = *(const uint2*)(p);
    uint2 hi = *(const uint2*)(p + 4);
    union { uint4 u; bf16x8 v; } x;
    x.u = make_uint4(lo.x, lo.y, hi.x, hi.y);
    return x.v;
}
__device__ __forceinline__ void wr8(u16t* dst, uint4 v, int i) {
    const u16t* s = (const u16t*)&v;
    #pragma unroll
    for (int c = 0; c < 8; ++c) dst[c * KP + i] = s[c];
}

// ============================================================
// K1: grad row moments -> ll (out), GH = bf16(a*grad), col partials CP.
// grid 2048 = (32 chunks x 64 n), block 256.
// ============================================================
__global__ __launch_bounds__(256) void k_prep(
    const float* __restrict__ grad, const float* __restrict__ L0,
    float* __restrict__ out, u16t* __restrict__ GH, float* __restrict__ CP)
{
    const int bid = blockIdx.x;
    const int n = bid & 63;
    const int chunk = bid >> 6;
    const int wave = threadIdx.x >> 6, lane = threadIdx.x & 63;
    const float* gb = grad + ((size_t)n << 18);
    u16t* GHn = GH + ((size_t)n << 18);

    float4 cacc = {0.f, 0.f, 0.f, 0.f};
    const int i0 = chunk * 32 + wave * 8;
    #pragma unroll
    for (int r = 0; r < 8; ++r) {
        const int i = i0 + r;
        const float4 v = *(const float4*)(gb + (size_t)i * 256 + lane * 4);
        float s = v.x*v.x + v.y*v.y + v.z*v.z + v.w*v.w;
        cacc.x += v.x*v.x; cacc.y += v.y*v.y; cacc.z += v.z*v.z; cacc.w += v.w*v.w;
        #pragma unroll
        for (int off = 32; off; off >>= 1) s += __shfl_xor(s, off);
        const float l0 = L0[n * DIN + i];
        const float ll = fmaxf(l0, 0.5f * l0 + s * (0.5f / DOUT));
        const float a  = rsqrtf(sqrtf(ll));
        ushort4 g4v = { f2b(v.x*a), f2b(v.y*a), f2b(v.z*a), f2b(v.w*a) };
        *(ushort4*)(GHn + (size_t)i * 256 + lane * 4) = g4v;
        if (lane == 0) out[OUT_LL + n * DIN + i] = ll;
    }
    const int slot = chunk * 4 + wave;
    *(float4*)(CP + ((size_t)(n * 128 + slot)) * 256 + lane * 4) = cacc;
}

// ============================================================
// K2: reduce 128 col partials -> rr (out), BS = rr^-1/4 ; copy state
// ============================================================
__global__ __launch_bounds__(256) void k_cols(
    const float* __restrict__ R0, const float* __restrict__ state,
    float* __restrict__ out, float* __restrict__ BS, const float* __restrict__ CP)
{
    const int n = blockIdx.x, o = threadIdx.x;
    const float* cp = CP + (size_t)n * 128 * 256 + o;
    float s = 0.f;
    #pragma unroll 8
    for (int k = 0; k < 128; ++k) s += cp[k * 256];
    const float r0 = R0[n * DOUT + o];
    const float rr = fmaxf(r0, 0.5f * r0 + s * (0.5f / DIN));
    out[OUT_RR + n * DOUT + o] = rr;
    BS[n * DOUT + o] = rsqrtf(sqrtf(rr));
    if (n == 0 && o == 0) out[OUT_STATE] = state[0];
}

// ============================================================
// G1 (k_T): TT[o][p] = b[o] * sum_i GH[i][o] * M[i][p]
// tile 128o x 64p, BK=64. grid 512 = (8 tiles x 64 n). 4 waves 2x2.
// ============================================================
__global__ __launch_bounds__(256, 4) void k_T(
    const u16t* __restrict__ GH, const float* __restrict__ M,
    const float* __restrict__ BS, u16t* __restrict__ TT)
{
    __shared__ u16t sA[128 * KP];   // [o][i]
    __shared__ u16t sB[64 * KP];    // [p][i]
    const int bid = blockIdx.x;
    const int n = bid & 63;
    const int tile = bid >> 6;                  // 0..7
    const int o0 = (tile & 1) * 128, p0 = (tile >> 1) * 64;
    const int t = threadIdx.x, lane = t & 63, w = t >> 6;
    const int wr = w >> 1, wc = w & 1, t16 = lane & 15, g4 = lane >> 4;
    const u16t* GHn = GH + ((size_t)n << 18);
    const float* Mn = M + ((size_t)n << 18);
    uint4  rA[4];
    float4 rB[4];
    f32x4 acc[4][2] = {};

#define T_LOAD(ch) { const int ib_ = (ch) * 64; \
    _Pragma("unroll") for (int j = 0; j < 4; ++j) { \
        const int s = j * 256 + t; \
        const int ia = (s & 31) | ((s >> 9) << 5), c8 = ((s >> 5) & 15) * 8; \
        rA[j] = *(const uint4*)(GHn + (size_t)(ib_ + ia) * 256 + o0 + c8); \
        const int c4 = ((s >> 5) & 15) * 4; \
        rB[j] = *(const float4*)(Mn + (size_t)(ib_ + ia) * 256 + p0 + c4); } }

    T_LOAD(0);
    for (int ch = 0; ch < 16; ++ch) {
        __syncthreads();
        #pragma unroll
        for (int j = 0; j < 4; ++j) {
            const int s = j * 256 + t;
            const int ia = (s & 31) | ((s >> 9) << 5), c8 = ((s >> 5) & 15) * 8;
            wr8(sA + c8 * KP, rA[j], ia);
            const int c4 = ((s >> 5) & 15) * 4;
            const float4 v = rB[j];
            sB[(c4+0)*KP + ia] = f2b(v.x);
            sB[(c4+1)*KP + ia] = f2b(v.y);
            sB[(c4+2)*KP + ia] = f2b(v.z);
            sB[(c4+3)*KP + ia] = f2b(v.w);
        }
        __syncthreads();
        if (ch < 15) T_LOAD(ch + 1);            // overlaps MFMA phase
        #pragma unroll
        for (int kb = 0; kb < 2; ++kb) {
            const int ko = kb * 32 + g4 * 8;
            bf16x8 fa[4], fb[2];
            #pragma unroll
            for (int fm = 0; fm < 4; ++fm)
                fa[fm] = ld_frag(sA + (wr*64 + fm*16 + t16) * KP + ko);
            #pragma unroll
            for (int fn = 0; fn < 2; ++fn)
                fb[fn] = ld_frag(sB + (wc*32 + fn*16 + t16) * KP + ko);
            #pragma unroll
            for (int fm = 0; fm < 4; ++fm)
                #pragma unroll
                for (int fn = 0; fn < 2; ++fn)
                    acc[fm][fn] = __builtin_amdgcn_mfma_f32_16x16x32_bf16(fa[fm], fb[fn], acc[fm][fn], 0, 0, 0);
        }
    }
    const float* bs = BS + n * DOUT;
    u16t* TTn = TT + ((size_t)n << 16);
    #pragma unroll
    for (int fm = 0; fm < 4; ++fm)
        #pragma unroll
        for (int fn = 0; fn < 2; ++fn) {
            const int p = p0 + wc*32 + fn*16 + t16;
            #pragma unroll
            for (int r = 0; r < 4; ++r) {
                const int o = o0 + wr*64 + fm*16 + g4*4 + r;
                TTn[o * 256 + p] = f2b(acc[fm][fn][r] * bs[o]);
            }
        }
}

// ============================================================
// G2 (k_fuse): Mnew[i][o] = M[i][o] + EPS*( sum_p M[i][p]*TT[o][p]
//                                           - b_o * a_i*grad[i][o] )
// (= A; the QR/Newton correction is O(5e-5) because M^T M = I + O(1e-6),
//  so E = (A^T A - I)/2 ~ EPS^2 * P^T P -> negligible. fp32 out.)
// tile 128i x 128o, K=256 (4 chunks). grid 1024 = (16 tiles x 64 n).
// ============================================================
__global__ __launch_bounds__(256, 3) void k_fuse(
    const float* __restrict__ M, const u16t* __restrict__ GH,
    const float* __restrict__ BS, const u16t* __restrict__ TT,
    float* __restrict__ out)
{
    __shared__ u16t sA[128 * KP];   // [i][p]
    __shared__ u16t sB[128 * KP];   // [o][p]
    const int bid = blockIdx.x;
    const int n = bid & 63;
    const int tile = bid >> 6;                  // 0..15: 8 i-tiles x 2 o-tiles
    const int i0 = (tile & 7) * 128, o0 = (tile >> 3) * 128;
    const int t = threadIdx.x, lane = t & 63, w = t >> 6;
    const int wr = w >> 1, wc = w & 1, t16 = lane & 15, g4 = lane >> 4;
    const float* Mn = M + ((size_t)n << 18);
    const u16t* GHn = GH + ((size_t)n << 18);
    const u16t* TTn = TT + ((size_t)n << 16);
    float4 rMa[8];
    uint4  rTb[4];
    f32x4 acc[4][4] = {};

#define FU_LOAD(ch) { const int pb_ = (ch) * 64; \
    _Pragma("unroll") for (int j = 0; j < 8; ++j) { \
        const int s = j * 256 + t, row = s >> 4, c4 = (s & 15) * 4; \
        rMa[j] = *(const float4*)(Mn + (size_t)(i0 + row) * 256 + pb_ + c4); } \
    _Pragma("unroll") for (int j = 0; j < 4; ++j) { \
        const int s = j * 256 + t, row = s >> 3, c8 = (s & 7) * 8; \
        rTb[j] = *(const uint4*)(TTn + (size_t)(o0 + row) * 256 + pb_ + c8); } }

    FU_LOAD(0);
    for (int ch = 0; ch < 4; ++ch) {
        __syncthreads();
        #pragma unroll
        for (int j = 0; j < 8; ++j) {
            const int s = j * 256 + t, row = s >> 4, c4 = (s & 15) * 4;
            const float4 v = rMa[j];
            ushort4 h = { f2b(v.x), f2b(v.y), f2b(v.z), f2b(v.w) };
            *(ushort4*)(sA + row * KP + c4) = h;
        }
        #pragma unroll
        for (int j = 0; j < 4; ++j) {
            const int s = j * 256 + t, row = s >> 3, c8 = (s & 7) * 8;
            *(uint2*)(sB + row * KP + c8)     = make_uint2(rTb[j].x, rTb[j].y);
            *(uint2*)(sB + row * KP + c8 + 4) = make_uint2(rTb[j].z, rTb[j].w);
        }
        __syncthreads();
        if (ch < 3) FU_LOAD(ch + 1);
        #pragma unroll
        for (int kb = 0; kb < 2; ++kb) {
            const int ko = kb * 32 + g4 * 8;
            bf16x8 fa[4], fb[4];
            #pragma unroll
            for (int fm = 0; fm < 4; ++fm)
                fa[fm] = ld_frag(sA + (wr*64 + fm*16 + t16) * KP + ko);
            #pragma unroll
            for (int fn = 0; fn < 4; ++fn)
                fb[fn] = ld_frag(sB + (wc*64 + fn*16 + t16) * KP + ko);
            #pragma unroll
            for (int fm = 0; fm < 4; ++fm)
                #pragma unroll
                for (int fn = 0; fn < 4; ++fn)
                    acc[fm][fn] = __builtin_amdgcn_mfma_f32_16x16x32_bf16(fa[fm], fb[fn], acc[fm][fn], 0, 0, 0);
        }
    }
    const float* bs = BS + n * DOUT;
    float* outn = out + ((size_t)n << 18);
    #pragma unroll
    for (int fm = 0; fm < 4; ++fm)
        #pragma unroll
        for (int fn = 0; fn < 4; ++fn) {
            const int o = o0 + wc*64 + fn*16 + t16;
            const float bo = bs[o];
            #pragma unroll
            for (int r = 0; r < 4; ++r) {
                const int i = i0 + wr*64 + fm*16 + g4*4 + r;
                const size_t idx = (size_t)i * 256 + o;
                outn[idx] = Mn[idx] + EPS * (acc[fm][fn][r] - bo * b2f(GHn[idx]));
            }
        }
}

extern "C" void kernel_launch(void* const* d_in, const int* in_sizes, int n_in,
                              void* d_out, int out_size, void* d_ws, size_t ws_size,
                              hipStream_t stream) {
    const float* grad  = (const float*)d_in[0];
    const float* M     = (const float*)d_in[1];
    const float* state = (const float*)d_in[2];
    const float* L0    = (const float*)d_in[3];
    const float* R0    = (const float*)d_in[4];
    float* out = (float*)d_out;
    char* wsb = (char*)d_ws;

    // region map (~48 MB):
    u16t* GH  = (u16t*)(wsb);                          // [0,32MB)   GH[n][i][o]
    u16t* TT  = (u16t*)(wsb + ((size_t)32 << 20));     // [32,40MB)  TT[n][o][p]
    float* CP = (float*)(wsb + ((size_t)40 << 20));    // [40,48MB)  CP[n][128][256]
    float* BS = (float*)(wsb + ((size_t)48 << 20));    // 64KB

    k_prep <<<2048, 256, 0, stream>>>(grad, L0, out, GH, CP);
    k_cols <<<64,   256, 0, stream>>>(R0, state, out, BS, CP);
    k_T    <<<512,  256, 0, stream>>>(GH, M, BS, TT);
    k_fuse <<<1024, 256, 0, stream>>>(M, GH, BS, TT, out);
}